// Round 4
// baseline (667.444 us; speedup 1.0000x reference)
//
#include <hip/hip_runtime.h>

// SelfAttention: out = softmax((xWq+bq)(xWk+bk)^T) @ Wout + bout
// B=8, N=2048, D=1024, fp32 in/out.
// Round 4: S = x(WqWk^T)x^T algebraic form (round 3) + 256^2 deep-pipelined
// phase-schedule split GEMM (T2 swizzle + T3/T4 counted vmcnt + T5 setprio).
// Score chain in bf16 hi/lo split (3 MFMAs per product); P@Wout plain bf16.

typedef unsigned short u16;
typedef __bf16 bf16x8 __attribute__((ext_vector_type(8)));
typedef float f32x4 __attribute__((ext_vector_type(4)));

#define BB 8
#define NN 2048
#define DD 1024
#define MT (BB * NN)
#define PSTRIDE 4096  // u16 elems per P row (in-place over fp32 S rows)

#define MFMA3(d, ah, al, bh, bl)                                         \
  d = __builtin_amdgcn_mfma_f32_16x16x32_bf16(ah, bh, d, 0, 0, 0);       \
  d = __builtin_amdgcn_mfma_f32_16x16x32_bf16(ah, bl, d, 0, 0, 0);       \
  d = __builtin_amdgcn_mfma_f32_16x16x32_bf16(al, bh, d, 0, 0, 0);

static __device__ __forceinline__ u16 f2bf(float f) {
  unsigned u = __builtin_bit_cast(unsigned, f);
  u += 0x7FFFu + ((u >> 16) & 1u);
  return (u16)(u >> 16);
}
static __device__ __forceinline__ float bf2f(u16 h) {
  unsigned u = ((unsigned)h) << 16;
  return __builtin_bit_cast(float, u);
}

static __device__ __forceinline__ void gload16(const void* g, void* l) {
  __builtin_amdgcn_global_load_lds((const __attribute__((address_space(1))) void*)g,
                                   (__attribute__((address_space(3))) void*)l, 16, 0, 0);
}

// bijective XCD swizzle over a 1-D grid (gridDim.x % 8 == 0 for all callers)
static __device__ __forceinline__ int swz_wg() {
  int nwg = gridDim.x;
  int orig = blockIdx.x;
  int q = nwg >> 3;
  return (orig & 7) * q + (orig >> 3);
}

// ---------------- 256x256 deep-pipelined split-GEMM core ------------------
// A,B: split bf16 planes, row-major [rows][1024], rows indexed by out row/col.
// 8 waves (2m x 4n), per-wave out 128x64 = acc[8][4]. K = 1024, BK = 32.
// LDS: 2 bufs x 4 planes x [256][32] u16 = 128 KiB.
// XOR-swizzle (T2): 16B chunk c of row r stored at c ^ ((r ^ r>>2) & 3).
#define SW(r) (((r) ^ ((r) >> 2)) & 3)

static __device__ __forceinline__ void stage_plane_sw(const u16* __restrict__ g0,
                                                      u16* lp0, int tid) {
#pragma unroll
  for (int j = 0; j < 2; j++) {
    int o = tid + j * 512;  // 16B-chunk index 0..1023 within plane
    int row = o >> 2, c = o & 3;
    const u16* g = g0 + (size_t)row * DD + ((c ^ SW(row)) << 3);  // inverse-swz src
    u16* lp = lp0 + (((tid >> 6) << 6) + j * 512) * 8;  // wave-uniform; HW adds lane*16B
    gload16(g, lp);
  }
}

static __device__ __forceinline__ bf16x8 rdfrag(const u16* plane, int row, int g4) {
  return *(const bf16x8*)&plane[row * 32 + ((g4 ^ SW(row)) << 3)];
}

// One K-tile: 4 phases. STG: stage tile t+2 planes (k offset kst) into Lc.
// VM: 8 = vmcnt(8) at ph3, 0 = vmcnt(0), -1 = none.
template <bool STG, int VM>
static __device__ __forceinline__ void tile_phases(
    u16* Lc, const u16* Ah, const u16* Al, const u16* Bh, const u16* Bl, int kst,
    f32x4 (&acc)[8][4], int tid, int wm, int wn, int r16, int g4) {
  u16* PA0 = Lc;
  u16* PA1 = Lc + 8192;
  u16* PB0 = Lc + 16384;
  u16* PB1 = Lc + 24576;
  bf16x8 xb[2][4], ya[2][4], yb[2][4];

  // ---- phase 0: read B(all) + A(mhalf0); MFMA quadrant (m0,n0)
#pragma unroll
  for (int fn = 0; fn < 4; fn++) {
    int rw = wn * 64 + fn * 16 + r16;
    xb[0][fn] = rdfrag(PB0, rw, g4);
    xb[1][fn] = rdfrag(PB1, rw, g4);
  }
#pragma unroll
  for (int fm = 0; fm < 4; fm++) {
    int rw = wm * 128 + fm * 16 + r16;
    ya[0][fm] = rdfrag(PA0, rw, g4);
    ya[1][fm] = rdfrag(PA1, rw, g4);
  }
  __builtin_amdgcn_s_barrier();
  asm volatile("s_waitcnt lgkmcnt(0)" ::: "memory");
  __builtin_amdgcn_sched_barrier(0);
  __builtin_amdgcn_s_setprio(1);
#pragma unroll
  for (int fm = 0; fm < 4; fm++)
#pragma unroll
    for (int fn = 0; fn < 2; fn++) {
      MFMA3(acc[fm][fn], ya[0][fm], ya[1][fm], xb[0][fn], xb[1][fn]);
    }
  __builtin_amdgcn_s_setprio(0);
  __builtin_amdgcn_s_barrier();

  // ---- phase 1: read A(mhalf1); MFMA (m0,n1) from regs; drain reads at end
#pragma unroll
  for (int fm = 0; fm < 4; fm++) {
    int rw = wm * 128 + 64 + fm * 16 + r16;
    yb[0][fm] = rdfrag(PA0, rw, g4);
    yb[1][fm] = rdfrag(PA1, rw, g4);
  }
  __builtin_amdgcn_s_barrier();
  __builtin_amdgcn_s_setprio(1);
#pragma unroll
  for (int fm = 0; fm < 4; fm++)
#pragma unroll
    for (int fn = 2; fn < 4; fn++) {
      MFMA3(acc[fm][fn], ya[0][fm], ya[1][fm], xb[0][fn], xb[1][fn]);
    }
  __builtin_amdgcn_s_setprio(0);
  asm volatile("s_waitcnt lgkmcnt(0)" ::: "memory");  // yb drained before A overwrite
  __builtin_amdgcn_sched_barrier(0);
  __builtin_amdgcn_s_barrier();

  // ---- phase 2: stage next A planes (A fully consumed); MFMA (m1,n0)
  if (STG) {
    stage_plane_sw(Ah + kst, PA0, tid);
    stage_plane_sw(Al + kst, PA1, tid);
  }
  __builtin_amdgcn_s_barrier();
  __builtin_amdgcn_s_setprio(1);
#pragma unroll
  for (int fm = 0; fm < 4; fm++)
#pragma unroll
    for (int fn = 0; fn < 2; fn++) {
      MFMA3(acc[fm + 4][fn], yb[0][fm], yb[1][fm], xb[0][fn], xb[1][fn]);
    }
  __builtin_amdgcn_s_setprio(0);
  __builtin_amdgcn_s_barrier();

  // ---- phase 3: stage next B planes; counted vmcnt; MFMA (m1,n1)
  if (STG) {
    stage_plane_sw(Bh + kst, PB0, tid);
    stage_plane_sw(Bl + kst, PB1, tid);
  }
  if (VM == 8) {
    asm volatile("s_waitcnt vmcnt(8)" ::: "memory");
  } else if (VM == 0) {
    asm volatile("s_waitcnt vmcnt(0)" ::: "memory");
  }
  __builtin_amdgcn_s_barrier();
  __builtin_amdgcn_s_setprio(1);
#pragma unroll
  for (int fm = 0; fm < 4; fm++)
#pragma unroll
    for (int fn = 2; fn < 4; fn++) {
      MFMA3(acc[fm + 4][fn], yb[0][fm], yb[1][fm], xb[0][fn], xb[1][fn]);
    }
  __builtin_amdgcn_s_setprio(0);
  __builtin_amdgcn_s_barrier();
}

static __device__ __forceinline__ void mm8_core(u16* L, const u16* Ah, const u16* Al,
                                                const u16* Bh, const u16* Bl,
                                                f32x4 (&acc)[8][4], int tid) {
  int lane = tid & 63, r16 = lane & 15, g4 = lane >> 4;
  int w = tid >> 6, wm = w >> 2, wn = w & 3;
  u16* L0 = L;
  u16* L1 = L + 4 * 8192;
  // prologue: tile0 -> buf0, tile1 -> buf1 (16 gloads/thread)
  stage_plane_sw(Ah + 0, L0 + 0, tid);
  stage_plane_sw(Al + 0, L0 + 8192, tid);
  stage_plane_sw(Bh + 0, L0 + 16384, tid);
  stage_plane_sw(Bl + 0, L0 + 24576, tid);
  stage_plane_sw(Ah + 32, L1 + 0, tid);
  stage_plane_sw(Al + 32, L1 + 8192, tid);
  stage_plane_sw(Bh + 32, L1 + 16384, tid);
  stage_plane_sw(Bl + 32, L1 + 24576, tid);
  asm volatile("s_waitcnt vmcnt(8)" ::: "memory");
  __builtin_amdgcn_s_barrier();
#pragma unroll 1
  for (int i = 0; i < 15; i++) {
    int t0 = 2 * i;
    tile_phases<true, 8>(L0, Ah, Al, Bh, Bl, (t0 + 2) * 32, acc, tid, wm, wn, r16, g4);
    tile_phases<true, 8>(L1, Ah, Al, Bh, Bl, (t0 + 3) * 32, acc, tid, wm, wn, r16, g4);
  }
  tile_phases<false, 0>(L0, Ah, Al, Bh, Bl, 0, acc, tid, wm, wn, r16, g4);   // t=30
  tile_phases<false, -1>(L1, Ah, Al, Bh, Bl, 0, acc, tid, wm, wn, r16, g4);  // t=31
}

// ---- S[b] = y[b] @ x[b]^T (fp32 out). grid = nb*64 blocks of 512 ---------
__launch_bounds__(512, 2)
__global__ void k_gemm_s8(const u16* __restrict__ yh, const u16* __restrict__ yl,
                          const u16* __restrict__ xh, const u16* __restrict__ xl,
                          float* __restrict__ S) {
  __shared__ __attribute__((aligned(16))) u16 lds[2][4][8192];
  int wg = swz_wg();
  int nt = wg & 7, mtot = wg >> 3;
  int b = mtot >> 3, mt = mtot & 7;
  const size_t po = (size_t)b * NN * DD;
  const u16* Ah = yh + po + (size_t)(mt * 256) * DD;
  const u16* Al = yl + po + (size_t)(mt * 256) * DD;
  const u16* Bh = xh + po + (size_t)(nt * 256) * DD;
  const u16* Bl = xl + po + (size_t)(nt * 256) * DD;
  int tid = threadIdx.x;
  f32x4 acc[8][4] = {};
  mm8_core(&lds[0][0][0], Ah, Al, Bh, Bl, acc, tid);
  int lane = tid & 63, r16 = lane & 15, g4 = lane >> 4;
  int w = tid >> 6, wm = w >> 2, wn = w & 3;
  float* Sb = S + (size_t)b * NN * NN;
#pragma unroll
  for (int fm = 0; fm < 8; fm++)
#pragma unroll
    for (int fn = 0; fn < 4; fn++) {
      int col = nt * 256 + wn * 64 + fn * 16 + r16;
      int row = mt * 256 + wm * 128 + fm * 16 + g4 * 4;
#pragma unroll
      for (int i2 = 0; i2 < 4; i2++)
        Sb[(size_t)(row + i2) * NN + col] = acc[fm][fn][i2];
    }
}

// ---- C = A @ B^T with split bf16 planes out (y and Mt GEMMs) -------------
// grid = (M/256)*(Nout/256); Nout = 1024 -> nt = wg & 3.
__launch_bounds__(512, 2)
__global__ void k_gemm_y8(const u16* __restrict__ ah_g, const u16* __restrict__ al_g,
                          const u16* __restrict__ bh_g, const u16* __restrict__ bl_g,
                          u16* __restrict__ ohi, u16* __restrict__ olo) {
  __shared__ __attribute__((aligned(16))) u16 lds[2][4][8192];
  int wg = swz_wg();
  int nt = wg & 3, mt = wg >> 2;
  const u16* Ah = ah_g + (size_t)(mt * 256) * DD;
  const u16* Al = al_g + (size_t)(mt * 256) * DD;
  const u16* Bh = bh_g + (size_t)(nt * 256) * DD;
  const u16* Bl = bl_g + (size_t)(nt * 256) * DD;
  int tid = threadIdx.x;
  f32x4 acc[8][4] = {};
  mm8_core(&lds[0][0][0], Ah, Al, Bh, Bl, acc, tid);
  int lane = tid & 63, r16 = lane & 15, g4 = lane >> 4;
  int w = tid >> 6, wm = w >> 2, wn = w & 3;
#pragma unroll
  for (int fm = 0; fm < 8; fm++)
#pragma unroll
    for (int fn = 0; fn < 4; fn++) {
      int col = nt * 256 + wn * 64 + fn * 16 + r16;
      int row = mt * 256 + wm * 128 + fm * 16 + g4 * 4;
#pragma unroll
      for (int i2 = 0; i2 < 4; i2++) {
        float v = acc[fm][fn][i2];
        u16 h = f2bf(v);
        size_t o = (size_t)(row + i2) * DD + col;
        ohi[o] = h;
        olo[o] = f2bf(v - bf2f(h));
      }
    }
}

// ---- prep: split fp32 -> hi/lo bf16 planes -------------------------------
__global__ void k_split(const float* __restrict__ x, u16* __restrict__ hi,
                        u16* __restrict__ lo, long n4) {
  long i = (long)blockIdx.x * blockDim.x + threadIdx.x;
  long stride = (long)gridDim.x * blockDim.x;
  for (; i < n4; i += stride) {
    float4 v = ((const float4*)x)[i];
    u16 h0 = f2bf(v.x), h1 = f2bf(v.y), h2 = f2bf(v.z), h3 = f2bf(v.w);
    ushort4 hv; hv.x = h0; hv.y = h1; hv.z = h2; hv.w = h3;
    ushort4 lv;
    lv.x = f2bf(v.x - bf2f(h0)); lv.y = f2bf(v.y - bf2f(h1));
    lv.z = f2bf(v.z - bf2f(h2)); lv.w = f2bf(v.w - bf2f(h3));
    ((ushort4*)hi)[i] = hv;
    ((ushort4*)lo)[i] = lv;
  }
}

// ---- prep: transpose RxC fp32 -> CxR bf16 (hi only) ----------------------
__global__ void k_transpose_split(const float* __restrict__ W, u16* __restrict__ thi,
                                  int R, int C) {
  __shared__ float tile[32][33];
  int c0 = blockIdx.x * 32, r0 = blockIdx.y * 32;
  int tx = threadIdx.x, ty = threadIdx.y;  // block (32,8)
#pragma unroll
  for (int i = 0; i < 4; i++)
    tile[ty + i * 8][tx] = W[(size_t)(r0 + ty + i * 8) * C + c0 + tx];
  __syncthreads();
#pragma unroll
  for (int i = 0; i < 4; i++) {
    float v = tile[tx][ty + i * 8];
    thi[(size_t)(c0 + ty + i * 8) * R + r0 + tx] = f2bf(v);
  }
}

// ---- matvec: out[r] = A[r,:] . v  (wave per row) -------------------------
__global__ void k_matvec(const float* __restrict__ A, const float* __restrict__ v,
                         float* __restrict__ out, int cols) {
  int w = threadIdx.x >> 6, lane = threadIdx.x & 63;
  int row = blockIdx.x * 4 + w;
  const float4* Ar = (const float4*)(A + (size_t)row * cols);
  const float4* vv = (const float4*)v;
  float s = 0.f;
  for (int j = lane; j < cols / 4; j += 64) {
    float4 a = Ar[j], b = vv[j];
    s += a.x * b.x + a.y * b.y + a.z * b.z + a.w * b.w;
  }
#pragma unroll
  for (int o = 32; o > 0; o >>= 1) s += __shfl_xor(s, o);
  if (lane == 0) out[row] = s;
}

// ---- softmax rows of S (+ per-col bias c2) -> P bf16 IN PLACE ------------
__global__ void k_softmax(float* __restrict__ S, const float* __restrict__ c2, int nrows) {
  int w = threadIdx.x >> 6, lane = threadIdx.x & 63;
  int row = blockIdx.x * 4 + w;
  if (row >= nrows) return;
  const float4* Sr = (const float4*)(S + (size_t)row * NN);
  const float4* c2b = (const float4*)(c2 + ((size_t)(row >> 11) << 11));
  float4 v[8];
  float mx = -3.4e38f;
#pragma unroll
  for (int j = 0; j < 8; j++) {
    v[j] = Sr[j * 64 + lane];
    float4 c = c2b[j * 64 + lane];
    v[j].x += c.x; v[j].y += c.y; v[j].z += c.z; v[j].w += c.w;
    mx = fmaxf(mx, fmaxf(fmaxf(v[j].x, v[j].y), fmaxf(v[j].z, v[j].w)));
  }
#pragma unroll
  for (int o = 32; o > 0; o >>= 1) mx = fmaxf(mx, __shfl_xor(mx, o));
  float e[32];
  float sum = 0.f;
#pragma unroll
  for (int j = 0; j < 8; j++) {
    e[j * 4 + 0] = __expf(v[j].x - mx);
    e[j * 4 + 1] = __expf(v[j].y - mx);
    e[j * 4 + 2] = __expf(v[j].z - mx);
    e[j * 4 + 3] = __expf(v[j].w - mx);
    sum += e[j * 4 + 0] + e[j * 4 + 1] + e[j * 4 + 2] + e[j * 4 + 3];
  }
#pragma unroll
  for (int o = 32; o > 0; o >>= 1) sum += __shfl_xor(sum, o);
  float inv = 1.0f / sum;  // depends on every lane's loads -> safe to overwrite row
  ushort4* Pr = (ushort4*)((u16*)S + (size_t)row * PSTRIDE);
#pragma unroll
  for (int j = 0; j < 8; j++) {
    ushort4 pv;
    pv.x = f2bf(e[j * 4 + 0] * inv);
    pv.y = f2bf(e[j * 4 + 1] * inv);
    pv.z = f2bf(e[j * 4 + 2] * inv);
    pv.w = f2bf(e[j * 4 + 3] * inv);
    Pr[j * 64 + lane] = pv;
  }
}

// ---- out[b] = P[b] @ Wout + bout (plain bf16, m97 structure) -------------
static __device__ __forceinline__ void stage_tile(const u16* __restrict__ gsrc,
                                                  u16* plane, int t, int ldg) {
  int w = t >> 6;
#pragma unroll
  for (int j = 0; j < 2; j++) {
    int idx = t + j * 256;
    const u16* g = gsrc + (size_t)(idx >> 2) * ldg + (idx & 3) * 8;
    u16* lp = plane + (w * 64 + j * 256) * 8;
    gload16(g, lp);
  }
}

__launch_bounds__(256)
__global__ void k_gemm_out(const u16* __restrict__ P, const u16* __restrict__ woutT,
                           const float* __restrict__ bout, float* __restrict__ out) {
  __shared__ __attribute__((aligned(16))) u16 lds[2][128][32];
  int wg = swz_wg();
  int b = wg >> 7, dt = wg & 7, ntt = (wg >> 3) & 15;
  const u16* Pb = P + (size_t)b * NN * PSTRIDE;
  float* ob = out + (size_t)b * NN * DD;

  int t = threadIdx.x, lane = t & 63, w = t >> 6;
  int wr = w >> 1, wc = w & 1, r16 = lane & 15, g = lane >> 4;

  f32x4 acc[4][4] = {};

  for (int k0 = 0; k0 < NN; k0 += 32) {
    stage_tile(Pb + (size_t)(ntt * 128) * PSTRIDE + k0, &lds[0][0][0], t, PSTRIDE);
    stage_tile(woutT + (size_t)(dt * 128) * NN + k0, &lds[1][0][0], t, NN);
    __syncthreads();
    bf16x8 bh[4];
#pragma unroll
    for (int fn = 0; fn < 4; fn++)
      bh[fn] = *(const bf16x8*)&lds[1][wc * 64 + fn * 16 + r16][g * 8];
#pragma unroll
    for (int fm = 0; fm < 4; fm++) {
      bf16x8 ah = *(const bf16x8*)&lds[0][wr * 64 + fm * 16 + r16][g * 8];
#pragma unroll
      for (int fn = 0; fn < 4; fn++)
        acc[fm][fn] = __builtin_amdgcn_mfma_f32_16x16x32_bf16(ah, bh[fn], acc[fm][fn], 0, 0, 0);
    }
    __syncthreads();
  }
#pragma unroll
  for (int fm = 0; fm < 4; fm++) {
#pragma unroll
    for (int fn = 0; fn < 4; fn++) {
      int col = dt * 128 + wc * 64 + fn * 16 + r16;
      float bv = bout[col];
      int row = ntt * 128 + wr * 64 + fm * 16 + g * 4;
#pragma unroll
      for (int i = 0; i < 4; i++)
        ob[(size_t)(row + i) * DD + col] = acc[fm][fn][i] + bv;
    }
  }
}

extern "C" void kernel_launch(void* const* d_in, const int* in_sizes, int n_in,
                              void* d_out, int out_size, void* d_ws, size_t ws_size,
                              hipStream_t stream) {
  const float* x = (const float*)d_in[0];
  const float* Wq = (const float*)d_in[1];
  const float* bq = (const float*)d_in[2];
  const float* Wk = (const float*)d_in[3];
  const float* bk = (const float*)d_in[4];
  const float* Wout = (const float*)d_in[5];
  const float* bout = (const float*)d_in[6];
  float* out = (float*)d_out;
  char* ws = (char*)d_ws;

  const size_t MB = 1ull << 20;
  // prep region [0,12MB): Mt planes, woutT, v2, c2
  u16* mth = (u16*)(ws + 0 * MB);
  u16* mtl = (u16*)(ws + 2 * MB);
  u16* woutT = (u16*)(ws + 4 * MB);            // 4 MiB [1024][2048]
  float* v2 = (float*)(ws + 8 * MB);           // 4 KiB
  float* c2 = (float*)(ws + 8 * MB + 65536);   // 64 KiB
  char* base = ws + 12 * MB;

  dim3 tb(32, 8, 1);

  if (ws_size >= 204 * MB) {
    // Tier A: xh/xl [0,64), yh/yl [64,128), S/scratch [128,192)
    u16* xh = (u16*)(base);
    u16* xl = (u16*)(base + 32 * MB);
    u16* yh = (u16*)(base + 64 * MB);
    u16* yl = (u16*)(base + 96 * MB);
    char* R = base + 128 * MB;  // 64 MiB scratch: Wq/Wk planes, then S
    u16* wqh = (u16*)(R);
    u16* wql = (u16*)(R + 2 * MB);
    u16* wkh = (u16*)(R + 4 * MB);
    u16* wkl = (u16*)(R + 6 * MB);
    float* S = (float*)R;

    // prep
    k_split<<<256, 256, 0, stream>>>(Wq, wqh, wql, (long)DD * DD / 4);
    k_split<<<256, 256, 0, stream>>>(Wk, wkh, wkl, (long)DD * DD / 4);
    k_gemm_y8<<<16, 512, 0, stream>>>(wkh, wkl, wqh, wql, mth, mtl);  // Mt = Wk@Wq^T
    k_transpose_split<<<dim3(32, 64, 1), tb, 0, stream>>>(Wout, woutT, 2048, 1024);
    k_matvec<<<256, 256, 0, stream>>>(Wk, bq, v2, DD);
    k_matvec<<<4096, 256, 0, stream>>>(x, v2, c2, DD);
    k_split<<<2048, 256, 0, stream>>>(x, xh, xl, (long)MT * DD / 4);
    // y = x @ Mt^T
    k_gemm_y8<<<256, 512, 0, stream>>>(xh, xl, mth, mtl, yh, yl);
    // per 4-batch half: S, softmax, out
    for (int h = 0; h < 2; h++) {
      size_t qo = (size_t)h * 4 * NN * DD;
      k_gemm_s8<<<256, 512, 0, stream>>>(yh + qo, yl + qo, xh + qo, xl + qo, S);
      k_softmax<<<4 * NN / 4, 256, 0, stream>>>(S, c2 + (size_t)h * 4 * NN, 4 * NN);
      k_gemm_out<<<4 * 128, 256, 0, stream>>>((const u16*)S, woutT, bout, out + qo);
    }
  } else if (ws_size >= 156 * MB) {
    // Tier B: xh/xl [0,64), yh/yl [64,128), S 16MB at [128,144)
    u16* xh = (u16*)(base);
    u16* xl = (u16*)(base + 32 * MB);
    u16* yh = (u16*)(base + 64 * MB);
    u16* yl = (u16*)(base + 96 * MB);
    char* R = base + 128 * MB;
    u16* wqh = (u16*)(R);
    u16* wql = (u16*)(R + 2 * MB);
    u16* wkh = (u16*)(R + 4 * MB);
    u16* wkl = (u16*)(R + 6 * MB);
    float* S = (float*)R;

    k_split<<<256, 256, 0, stream>>>(Wq, wqh, wql, (long)DD * DD / 4);
    k_split<<<256, 256, 0, stream>>>(Wk, wkh, wkl, (long)DD * DD / 4);
    k_gemm_y8<<<16, 512, 0, stream>>>(wkh, wkl, wqh, wql, mth, mtl);
    k_transpose_split<<<dim3(32, 64, 1), tb, 0, stream>>>(Wout, woutT, 2048, 1024);
    k_matvec<<<256, 256, 0, stream>>>(Wk, bq, v2, DD);
    k_matvec<<<4096, 256, 0, stream>>>(x, v2, c2, DD);
    k_split<<<2048, 256, 0, stream>>>(x, xh, xl, (long)MT * DD / 4);
    k_gemm_y8<<<256, 512, 0, stream>>>(xh, xl, mth, mtl, yh, yl);
    for (int b = 0; b < BB; b++) {
      size_t qo = (size_t)b * NN * DD;
      k_gemm_s8<<<64, 512, 0, stream>>>(yh + qo, yl + qo, xh + qo, xl + qo, S);
      k_softmax<<<NN / 4, 256, 0, stream>>>(S, c2 + (size_t)b * NN, NN);
      k_gemm_out<<<128, 256, 0, stream>>>((const u16*)S, woutT, bout, out + qo);
    }
  } else {
    // Tier C (60 MiB): per 2-batch chunk, xh/xl 16MB, yh/yl 16MB, S 16MB
    u16* xh = (u16*)(base);
    u16* xl = (u16*)(base + 8 * MB);
    u16* yh = (u16*)(base + 16 * MB);
    u16* yl = (u16*)(base + 24 * MB);
    char* R = base + 32 * MB;
    u16* wqh = (u16*)(R);
    u16* wql = (u16*)(R + 2 * MB);
    u16* wkh = (u16*)(R + 4 * MB);
    u16* wkl = (u16*)(R + 6 * MB);
    float* S = (float*)R;

    k_split<<<256, 256, 0, stream>>>(Wq, wqh, wql, (long)DD * DD / 4);
    k_split<<<256, 256, 0, stream>>>(Wk, wkh, wkl, (long)DD * DD / 4);
    k_gemm_y8<<<16, 512, 0, stream>>>(wkh, wkl, wqh, wql, mth, mtl);
    k_transpose_split<<<dim3(32, 64, 1), tb, 0, stream>>>(Wout, woutT, 2048, 1024);
    k_matvec<<<256, 256, 0, stream>>>(Wk, bq, v2, DD);
    k_matvec<<<4096, 256, 0, stream>>>(x, v2, c2, DD);
    for (int c = 0; c < 4; c++) {
      size_t xo = (size_t)c * 2 * NN * DD;
      k_split<<<1024, 256, 0, stream>>>(x + xo, xh, xl, (long)2 * NN * DD / 4);
      k_gemm_y8<<<64, 512, 0, stream>>>(xh, xl, mth, mtl, yh, yl);
      for (int bi = 0; bi < 2; bi++) {
        size_t lo = (size_t)bi * NN * DD;
        k_gemm_s8<<<64, 512, 0, stream>>>(yh + lo, yl + lo, xh + lo, xl + lo, S);
        k_softmax<<<NN / 4, 256, 0, stream>>>(S, c2 + (size_t)(c * 2 + bi) * NN, NN);
        k_gemm_out<<<128, 256, 0, stream>>>((const u16*)S, woutT, bout, out + xo + lo);
      }
    }
  }
}

// Round 5
// 522.716 us; speedup vs baseline: 1.2769x; 1.2769x over previous
//
#include <hip/hip_runtime.h>

// SelfAttention: out = softmax((xWq+bq)(xWk+bk)^T) @ Wout + bout
// B=8, N=2048, D=1024, fp32 in/out.
// Round 5: S = x(WqWk^T)x^T algebraic form + restructured 256^2 pipelined
// split GEMM: per-quadrant ds_reads, staging at natural plane-free points,
// no mid-phase drains, 6 barriers/tile, counted vmcnt(8), setprio on MFMA.
// Score chain bf16 hi/lo split (3 MFMAs per product); P@Wout plain bf16.

typedef unsigned short u16;
typedef __bf16 bf16x8 __attribute__((ext_vector_type(8)));
typedef float f32x4 __attribute__((ext_vector_type(4)));

#define BB 8
#define NN 2048
#define DD 1024
#define MT (BB * NN)
#define PSTRIDE 4096  // u16 elems per P row (in-place over fp32 S rows)

#define MFMA3(d, ah, al, bh, bl)                                         \
  d = __builtin_amdgcn_mfma_f32_16x16x32_bf16(ah, bh, d, 0, 0, 0);       \
  d = __builtin_amdgcn_mfma_f32_16x16x32_bf16(ah, bl, d, 0, 0, 0);       \
  d = __builtin_amdgcn_mfma_f32_16x16x32_bf16(al, bh, d, 0, 0, 0);

static __device__ __forceinline__ u16 f2bf(float f) {
  unsigned u = __builtin_bit_cast(unsigned, f);
  u += 0x7FFFu + ((u >> 16) & 1u);
  return (u16)(u >> 16);
}
static __device__ __forceinline__ float bf2f(u16 h) {
  unsigned u = ((unsigned)h) << 16;
  return __builtin_bit_cast(float, u);
}

static __device__ __forceinline__ void gload16(const void* g, void* l) {
  __builtin_amdgcn_global_load_lds((const __attribute__((address_space(1))) void*)g,
                                   (__attribute__((address_space(3))) void*)l, 16, 0, 0);
}

// bijective XCD swizzle over a 1-D grid (gridDim.x % 8 == 0 for all callers)
static __device__ __forceinline__ int swz_wg() {
  int nwg = gridDim.x;
  int orig = blockIdx.x;
  int q = nwg >> 3;
  return (orig & 7) * q + (orig >> 3);
}

// ---------------- 256x256 pipelined split-GEMM core -----------------------
// A,B: split bf16 planes, row-major [rows][1024], rows indexed by out row/col.
// 8 waves (2m x 4n), per-wave out 128x64 = acc[8][4]. K = 1024, BK = 32.
// LDS: 2 bufs x 4 planes x [256][32] u16 = 128 KiB.
// XOR-swizzle (T2): 16B chunk c of row r stored at c ^ ((r ^ r>>2) & 3).
#define SW(r) (((r) ^ ((r) >> 2)) & 3)

static __device__ __forceinline__ void stage_plane_sw(const u16* __restrict__ g0,
                                                      u16* lp0, int tid) {
#pragma unroll
  for (int j = 0; j < 2; j++) {
    int o = tid + j * 512;  // 16B-chunk index 0..1023 within plane
    int row = o >> 2, c = o & 3;
    const u16* g = g0 + (size_t)row * DD + ((c ^ SW(row)) << 3);  // inverse-swz src
    u16* lp = lp0 + (((tid >> 6) << 6) + j * 512) * 8;  // wave-uniform; HW adds lane*16B
    gload16(g, lp);
  }
}

static __device__ __forceinline__ bf16x8 rdfrag(const u16* plane, int row, int g4) {
  return *(const bf16x8*)&plane[row * 32 + ((g4 ^ SW(row)) << 3)];
}

// One K-tile, 4 phases. Reads per quadrant in its own phase; staging of tile
// t+2 at the planes' free points (B at ph2, A at ph3). VM: 8 / 0 / -1(none).
template <bool STG, int VM>
static __device__ __forceinline__ void tile4(
    u16* Lc, const u16* Ah, const u16* Al, const u16* Bh, const u16* Bl, int kst,
    f32x4 (&acc)[8][4], int tid, int wm, int wn, int r16, int g4) {
  u16* PA0 = Lc;
  u16* PA1 = Lc + 8192;
  u16* PB0 = Lc + 16384;
  u16* PB1 = Lc + 24576;
  bf16x8 a0[4], a1[4], b0[4], b1[4];

  // ---- phase 0: read A-half0 + B(n0-1); MFMA (m0, n0-1)
#pragma unroll
  for (int fm = 0; fm < 4; fm++) {
    int rw = wm * 128 + fm * 16 + r16;
    a0[fm] = rdfrag(PA0, rw, g4);
    a1[fm] = rdfrag(PA1, rw, g4);
  }
#pragma unroll
  for (int fn = 0; fn < 2; fn++) {
    int rw = wn * 64 + fn * 16 + r16;
    b0[fn] = rdfrag(PB0, rw, g4);
    b1[fn] = rdfrag(PB1, rw, g4);
  }
  __builtin_amdgcn_s_barrier();
  asm volatile("s_waitcnt lgkmcnt(0)" ::: "memory");
  __builtin_amdgcn_s_setprio(1);
#pragma unroll
  for (int fm = 0; fm < 4; fm++)
#pragma unroll
    for (int fn = 0; fn < 2; fn++) { MFMA3(acc[fm][fn], a0[fm], a1[fm], b0[fn], b1[fn]); }
  __builtin_amdgcn_s_setprio(0);
  // (no end barrier: next phase only reads long-staged LDS + registers)

  // ---- phase 1: read B(n2-3); MFMA (m0, n2-3)
#pragma unroll
  for (int fn = 2; fn < 4; fn++) {
    int rw = wn * 64 + fn * 16 + r16;
    b0[fn] = rdfrag(PB0, rw, g4);
    b1[fn] = rdfrag(PB1, rw, g4);
  }
  __builtin_amdgcn_s_barrier();
  asm volatile("s_waitcnt lgkmcnt(0)" ::: "memory");
  __builtin_amdgcn_s_setprio(1);
#pragma unroll
  for (int fm = 0; fm < 4; fm++)
#pragma unroll
    for (int fn = 2; fn < 4; fn++) { MFMA3(acc[fm][fn], a0[fm], a1[fm], b0[fn], b1[fn]); }
  __builtin_amdgcn_s_setprio(0);
  __builtin_amdgcn_s_barrier();  // R1: all waves' B reads drained -> B planes free

  // ---- phase 2: read A-half1; stage next B planes; MFMA (m1, n0-1)
#pragma unroll
  for (int fm = 0; fm < 4; fm++) {
    int rw = wm * 128 + 64 + fm * 16 + r16;
    a0[fm] = rdfrag(PA0, rw, g4);
    a1[fm] = rdfrag(PA1, rw, g4);
  }
  if (STG) {
    stage_plane_sw(Bh + kst, PB0, tid);
    stage_plane_sw(Bl + kst, PB1, tid);
  }
  __builtin_amdgcn_s_barrier();
  asm volatile("s_waitcnt lgkmcnt(0)" ::: "memory");
  __builtin_amdgcn_s_setprio(1);
#pragma unroll
  for (int fm = 0; fm < 4; fm++)
#pragma unroll
    for (int fn = 0; fn < 2; fn++) { MFMA3(acc[fm + 4][fn], a0[fm], a1[fm], b0[fn], b1[fn]); }
  __builtin_amdgcn_s_setprio(0);
  __builtin_amdgcn_s_barrier();  // R2: all waves' A reads drained -> A planes free

  // ---- phase 3: stage next A planes; counted vmcnt; MFMA (m1, n2-3)
  if (STG) {
    stage_plane_sw(Ah + kst, PA0, tid);
    stage_plane_sw(Al + kst, PA1, tid);
  }
  if (VM == 8) {
    asm volatile("s_waitcnt vmcnt(8)" ::: "memory");
  } else if (VM == 0) {
    asm volatile("s_waitcnt vmcnt(0)" ::: "memory");
  }
  __builtin_amdgcn_s_barrier();  // R3: next tile's buffer fully landed for all
  __builtin_amdgcn_s_setprio(1);
#pragma unroll
  for (int fm = 0; fm < 4; fm++)
#pragma unroll
    for (int fn = 2; fn < 4; fn++) { MFMA3(acc[fm + 4][fn], a0[fm], a1[fm], b0[fn], b1[fn]); }
  __builtin_amdgcn_s_setprio(0);
  // (no end barrier: next phase reads the other, long-ready buffer)
}

static __device__ __forceinline__ void mm8_core(u16* L, const u16* Ah, const u16* Al,
                                                const u16* Bh, const u16* Bl,
                                                f32x4 (&acc)[8][4], int tid) {
  int lane = tid & 63, r16 = lane & 15, g4 = lane >> 4;
  int w = tid >> 6, wm = w >> 2, wn = w & 3;
  u16* L0 = L;
  u16* L1 = L + 4 * 8192;
  // prologue: tile0 -> buf0, tile1 -> buf1 (16 gloads/thread)
  stage_plane_sw(Ah + 0, L0 + 0, tid);
  stage_plane_sw(Al + 0, L0 + 8192, tid);
  stage_plane_sw(Bh + 0, L0 + 16384, tid);
  stage_plane_sw(Bl + 0, L0 + 24576, tid);
  stage_plane_sw(Ah + 32, L1 + 0, tid);
  stage_plane_sw(Al + 32, L1 + 8192, tid);
  stage_plane_sw(Bh + 32, L1 + 16384, tid);
  stage_plane_sw(Bl + 32, L1 + 24576, tid);
  asm volatile("s_waitcnt vmcnt(8)" ::: "memory");
  __builtin_amdgcn_s_barrier();
#pragma unroll 1
  for (int i = 0; i < 15; i++) {
    int t0 = 2 * i;
    tile4<true, 8>(L0, Ah, Al, Bh, Bl, (t0 + 2) * 32, acc, tid, wm, wn, r16, g4);
    tile4<true, 8>(L1, Ah, Al, Bh, Bl, (t0 + 3) * 32, acc, tid, wm, wn, r16, g4);
  }
  tile4<false, 0>(L0, Ah, Al, Bh, Bl, 0, acc, tid, wm, wn, r16, g4);   // t=30
  tile4<false, -1>(L1, Ah, Al, Bh, Bl, 0, acc, tid, wm, wn, r16, g4);  // t=31
}

// ---- S[b] = y[b] @ x[b]^T (fp32 out). grid = nb*64 blocks of 512 ---------
__launch_bounds__(512, 2)
__global__ void k_gemm_s8(const u16* __restrict__ yh, const u16* __restrict__ yl,
                          const u16* __restrict__ xh, const u16* __restrict__ xl,
                          float* __restrict__ S) {
  __shared__ __attribute__((aligned(16))) u16 lds[2][4][8192];
  int wg = swz_wg();
  int nt = wg & 7, mtot = wg >> 3;
  int b = mtot >> 3, mt = mtot & 7;
  const size_t po = (size_t)b * NN * DD;
  const u16* Ah = yh + po + (size_t)(mt * 256) * DD;
  const u16* Al = yl + po + (size_t)(mt * 256) * DD;
  const u16* Bh = xh + po + (size_t)(nt * 256) * DD;
  const u16* Bl = xl + po + (size_t)(nt * 256) * DD;
  int tid = threadIdx.x;
  f32x4 acc[8][4] = {};
  mm8_core(&lds[0][0][0], Ah, Al, Bh, Bl, acc, tid);
  int lane = tid & 63, r16 = lane & 15, g4 = lane >> 4;
  int w = tid >> 6, wm = w >> 2, wn = w & 3;
  float* Sb = S + (size_t)b * NN * NN;
#pragma unroll
  for (int fm = 0; fm < 8; fm++)
#pragma unroll
    for (int fn = 0; fn < 4; fn++) {
      int col = nt * 256 + wn * 64 + fn * 16 + r16;
      int row = mt * 256 + wm * 128 + fm * 16 + g4 * 4;
#pragma unroll
      for (int i2 = 0; i2 < 4; i2++)
        Sb[(size_t)(row + i2) * NN + col] = acc[fm][fn][i2];
    }
}

// ---- C = A @ B^T with split bf16 planes out (y and Mt GEMMs) -------------
// grid = (M/256)*(Nout/256); Nout = 1024 -> nt = wg & 3.
__launch_bounds__(512, 2)
__global__ void k_gemm_y8(const u16* __restrict__ ah_g, const u16* __restrict__ al_g,
                          const u16* __restrict__ bh_g, const u16* __restrict__ bl_g,
                          u16* __restrict__ ohi, u16* __restrict__ olo) {
  __shared__ __attribute__((aligned(16))) u16 lds[2][4][8192];
  int wg = swz_wg();
  int nt = wg & 3, mt = wg >> 2;
  const u16* Ah = ah_g + (size_t)(mt * 256) * DD;
  const u16* Al = al_g + (size_t)(mt * 256) * DD;
  const u16* Bh = bh_g + (size_t)(nt * 256) * DD;
  const u16* Bl = bl_g + (size_t)(nt * 256) * DD;
  int tid = threadIdx.x;
  f32x4 acc[8][4] = {};
  mm8_core(&lds[0][0][0], Ah, Al, Bh, Bl, acc, tid);
  int lane = tid & 63, r16 = lane & 15, g4 = lane >> 4;
  int w = tid >> 6, wm = w >> 2, wn = w & 3;
#pragma unroll
  for (int fm = 0; fm < 8; fm++)
#pragma unroll
    for (int fn = 0; fn < 4; fn++) {
      int col = nt * 256 + wn * 64 + fn * 16 + r16;
      int row = mt * 256 + wm * 128 + fm * 16 + g4 * 4;
#pragma unroll
      for (int i2 = 0; i2 < 4; i2++) {
        float v = acc[fm][fn][i2];
        u16 h = f2bf(v);
        size_t o = (size_t)(row + i2) * DD + col;
        ohi[o] = h;
        olo[o] = f2bf(v - bf2f(h));
      }
    }
}

// ---- prep: split fp32 -> hi/lo bf16 planes -------------------------------
__global__ void k_split(const float* __restrict__ x, u16* __restrict__ hi,
                        u16* __restrict__ lo, long n4) {
  long i = (long)blockIdx.x * blockDim.x + threadIdx.x;
  long stride = (long)gridDim.x * blockDim.x;
  for (; i < n4; i += stride) {
    float4 v = ((const float4*)x)[i];
    u16 h0 = f2bf(v.x), h1 = f2bf(v.y), h2 = f2bf(v.z), h3 = f2bf(v.w);
    ushort4 hv; hv.x = h0; hv.y = h1; hv.z = h2; hv.w = h3;
    ushort4 lv;
    lv.x = f2bf(v.x - bf2f(h0)); lv.y = f2bf(v.y - bf2f(h1));
    lv.z = f2bf(v.z - bf2f(h2)); lv.w = f2bf(v.w - bf2f(h3));
    ((ushort4*)hi)[i] = hv;
    ((ushort4*)lo)[i] = lv;
  }
}

// ---- prep: transpose RxC fp32 -> CxR bf16 (hi only) ----------------------
__global__ void k_transpose_split(const float* __restrict__ W, u16* __restrict__ thi,
                                  int R, int C) {
  __shared__ float tile[32][33];
  int c0 = blockIdx.x * 32, r0 = blockIdx.y * 32;
  int tx = threadIdx.x, ty = threadIdx.y;  // block (32,8)
#pragma unroll
  for (int i = 0; i < 4; i++)
    tile[ty + i * 8][tx] = W[(size_t)(r0 + ty + i * 8) * C + c0 + tx];
  __syncthreads();
#pragma unroll
  for (int i = 0; i < 4; i++) {
    float v = tile[tx][ty + i * 8];
    thi[(size_t)(c0 + ty + i * 8) * R + r0 + tx] = f2bf(v);
  }
}

// ---- matvec: out[r] = A[r,:] . v  (wave per row) -------------------------
__global__ void k_matvec(const float* __restrict__ A, const float* __restrict__ v,
                         float* __restrict__ out, int cols) {
  int w = threadIdx.x >> 6, lane = threadIdx.x & 63;
  int row = blockIdx.x * 4 + w;
  const float4* Ar = (const float4*)(A + (size_t)row * cols);
  const float4* vv = (const float4*)v;
  float s = 0.f;
  for (int j = lane; j < cols / 4; j += 64) {
    float4 a = Ar[j], b = vv[j];
    s += a.x * b.x + a.y * b.y + a.z * b.z + a.w * b.w;
  }
#pragma unroll
  for (int o = 32; o > 0; o >>= 1) s += __shfl_xor(s, o);
  if (lane == 0) out[row] = s;
}

// ---- softmax rows of S (+ per-col bias c2) -> P bf16 IN PLACE ------------
__global__ void k_softmax(float* __restrict__ S, const float* __restrict__ c2, int nrows) {
  int w = threadIdx.x >> 6, lane = threadIdx.x & 63;
  int row = blockIdx.x * 4 + w;
  if (row >= nrows) return;
  const float4* Sr = (const float4*)(S + (size_t)row * NN);
  const float4* c2b = (const float4*)(c2 + ((size_t)(row >> 11) << 11));
  float4 v[8];
  float mx = -3.4e38f;
#pragma unroll
  for (int j = 0; j < 8; j++) {
    v[j] = Sr[j * 64 + lane];
    float4 c = c2b[j * 64 + lane];
    v[j].x += c.x; v[j].y += c.y; v[j].z += c.z; v[j].w += c.w;
    mx = fmaxf(mx, fmaxf(fmaxf(v[j].x, v[j].y), fmaxf(v[j].z, v[j].w)));
  }
#pragma unroll
  for (int o = 32; o > 0; o >>= 1) mx = fmaxf(mx, __shfl_xor(mx, o));
  float e[32];
  float sum = 0.f;
#pragma unroll
  for (int j = 0; j < 8; j++) {
    e[j * 4 + 0] = __expf(v[j].x - mx);
    e[j * 4 + 1] = __expf(v[j].y - mx);
    e[j * 4 + 2] = __expf(v[j].z - mx);
    e[j * 4 + 3] = __expf(v[j].w - mx);
    sum += e[j * 4 + 0] + e[j * 4 + 1] + e[j * 4 + 2] + e[j * 4 + 3];
  }
#pragma unroll
  for (int o = 32; o > 0; o >>= 1) sum += __shfl_xor(sum, o);
  float inv = 1.0f / sum;  // depends on every lane's loads -> safe to overwrite row
  ushort4* Pr = (ushort4*)((u16*)S + (size_t)row * PSTRIDE);
#pragma unroll
  for (int j = 0; j < 8; j++) {
    ushort4 pv;
    pv.x = f2bf(e[j * 4 + 0] * inv);
    pv.y = f2bf(e[j * 4 + 1] * inv);
    pv.z = f2bf(e[j * 4 + 2] * inv);
    pv.w = f2bf(e[j * 4 + 3] * inv);
    Pr[j * 64 + lane] = pv;
  }
}

// ---- out[b] = P[b] @ Wout + bout (plain bf16, m97 structure) -------------
static __device__ __forceinline__ void stage_tile(const u16* __restrict__ gsrc,
                                                  u16* plane, int t, int ldg) {
  int w = t >> 6;
#pragma unroll
  for (int j = 0; j < 2; j++) {
    int idx = t + j * 256;
    const u16* g = gsrc + (size_t)(idx >> 2) * ldg + (idx & 3) * 8;
    u16* lp = plane + (w * 64 + j * 256) * 8;
    gload16(g, lp);
  }
}

__launch_bounds__(256)
__global__ void k_gemm_out(const u16* __restrict__ P, const u16* __restrict__ woutT,
                           const float* __restrict__ bout, float* __restrict__ out) {
  __shared__ __attribute__((aligned(16))) u16 lds[2][128][32];
  int wg = swz_wg();
  int b = wg >> 7, dt = wg & 7, ntt = (wg >> 3) & 15;
  const u16* Pb = P + (size_t)b * NN * PSTRIDE;
  float* ob = out + (size_t)b * NN * DD;

  int t = threadIdx.x, lane = t & 63, w = t >> 6;
  int wr = w >> 1, wc = w & 1, r16 = lane & 15, g = lane >> 4;

  f32x4 acc[4][4] = {};

  for (int k0 = 0; k0 < NN; k0 += 32) {
    stage_tile(Pb + (size_t)(ntt * 128) * PSTRIDE + k0, &lds[0][0][0], t, PSTRIDE);
    stage_tile(woutT + (size_t)(dt * 128) * NN + k0, &lds[1][0][0], t, NN);
    __syncthreads();
    bf16x8 bh[4];
#pragma unroll
    for (int fn = 0; fn < 4; fn++)
      bh[fn] = *(const bf16x8*)&lds[1][wc * 64 + fn * 16 + r16][g * 8];
#pragma unroll
    for (int fm = 0; fm < 4; fm++) {
      bf16x8 ah = *(const bf16x8*)&lds[0][wr * 64 + fm * 16 + r16][g * 8];
#pragma unroll
      for (int fn = 0; fn < 4; fn++)
        acc[fm][fn] = __builtin_amdgcn_mfma_f32_16x16x32_bf16(ah, bh[fn], acc[fm][fn], 0, 0, 0);
    }
    __syncthreads();
  }
#pragma unroll
  for (int fm = 0; fm < 4; fm++) {
#pragma unroll
    for (int fn = 0; fn < 4; fn++) {
      int col = dt * 128 + wc * 64 + fn * 16 + r16;
      float bv = bout[col];
      int row = ntt * 128 + wr * 64 + fm * 16 + g * 4;
#pragma unroll
      for (int i = 0; i < 4; i++)
        ob[(size_t)(row + i) * DD + col] = acc[fm][fn][i] + bv;
    }
  }
}

extern "C" void kernel_launch(void* const* d_in, const int* in_sizes, int n_in,
                              void* d_out, int out_size, void* d_ws, size_t ws_size,
                              hipStream_t stream) {
  const float* x = (const float*)d_in[0];
  const float* Wq = (const float*)d_in[1];
  const float* bq = (const float*)d_in[2];
  const float* Wk = (const float*)d_in[3];
  const float* bk = (const float*)d_in[4];
  const float* Wout = (const float*)d_in[5];
  const float* bout = (const float*)d_in[6];
  float* out = (float*)d_out;
  char* ws = (char*)d_ws;

  const size_t MB = 1ull << 20;
  // prep region [0,12MB): Mt planes, woutT, v2, c2
  u16* mth = (u16*)(ws + 0 * MB);
  u16* mtl = (u16*)(ws + 2 * MB);
  u16* woutT = (u16*)(ws + 4 * MB);            // 4 MiB [1024][2048]
  float* v2 = (float*)(ws + 8 * MB);           // 4 KiB
  float* c2 = (float*)(ws + 8 * MB + 65536);   // 64 KiB
  char* base = ws + 12 * MB;

  dim3 tb(32, 8, 1);

  if (ws_size >= 204 * MB) {
    // Tier A: xh/xl [0,64), yh/yl [64,128), S/scratch [128,192)
    u16* xh = (u16*)(base);
    u16* xl = (u16*)(base + 32 * MB);
    u16* yh = (u16*)(base + 64 * MB);
    u16* yl = (u16*)(base + 96 * MB);
    char* R = base + 128 * MB;  // 64 MiB scratch: Wq/Wk planes, then S
    u16* wqh = (u16*)(R);
    u16* wql = (u16*)(R + 2 * MB);
    u16* wkh = (u16*)(R + 4 * MB);
    u16* wkl = (u16*)(R + 6 * MB);
    float* S = (float*)R;

    // prep
    k_split<<<256, 256, 0, stream>>>(Wq, wqh, wql, (long)DD * DD / 4);
    k_split<<<256, 256, 0, stream>>>(Wk, wkh, wkl, (long)DD * DD / 4);
    k_gemm_y8<<<16, 512, 0, stream>>>(wkh, wkl, wqh, wql, mth, mtl);  // Mt = Wk@Wq^T
    k_transpose_split<<<dim3(32, 64, 1), tb, 0, stream>>>(Wout, woutT, 2048, 1024);
    k_matvec<<<256, 256, 0, stream>>>(Wk, bq, v2, DD);
    k_matvec<<<4096, 256, 0, stream>>>(x, v2, c2, DD);
    k_split<<<2048, 256, 0, stream>>>(x, xh, xl, (long)MT * DD / 4);
    // y = x @ Mt^T
    k_gemm_y8<<<256, 512, 0, stream>>>(xh, xl, mth, mtl, yh, yl);
    // per 4-batch half: S, softmax, out
    for (int h = 0; h < 2; h++) {
      size_t qo = (size_t)h * 4 * NN * DD;
      k_gemm_s8<<<256, 512, 0, stream>>>(yh + qo, yl + qo, xh + qo, xl + qo, S);
      k_softmax<<<4 * NN / 4, 256, 0, stream>>>(S, c2 + (size_t)h * 4 * NN, 4 * NN);
      k_gemm_out<<<4 * 128, 256, 0, stream>>>((const u16*)S, woutT, bout, out + qo);
    }
  } else if (ws_size >= 156 * MB) {
    // Tier B: xh/xl [0,64), yh/yl [64,128), S 16MB at [128,144)
    u16* xh = (u16*)(base);
    u16* xl = (u16*)(base + 32 * MB);
    u16* yh = (u16*)(base + 64 * MB);
    u16* yl = (u16*)(base + 96 * MB);
    char* R = base + 128 * MB;
    u16* wqh = (u16*)(R);
    u16* wql = (u16*)(R + 2 * MB);
    u16* wkh = (u16*)(R + 4 * MB);
    u16* wkl = (u16*)(R + 6 * MB);
    float* S = (float*)R;

    k_split<<<256, 256, 0, stream>>>(Wq, wqh, wql, (long)DD * DD / 4);
    k_split<<<256, 256, 0, stream>>>(Wk, wkh, wkl, (long)DD * DD / 4);
    k_gemm_y8<<<16, 512, 0, stream>>>(wkh, wkl, wqh, wql, mth, mtl);
    k_transpose_split<<<dim3(32, 64, 1), tb, 0, stream>>>(Wout, woutT, 2048, 1024);
    k_matvec<<<256, 256, 0, stream>>>(Wk, bq, v2, DD);
    k_matvec<<<4096, 256, 0, stream>>>(x, v2, c2, DD);
    k_split<<<2048, 256, 0, stream>>>(x, xh, xl, (long)MT * DD / 4);
    k_gemm_y8<<<256, 512, 0, stream>>>(xh, xl, mth, mtl, yh, yl);
    for (int b = 0; b < BB; b++) {
      size_t qo = (size_t)b * NN * DD;
      k_gemm_s8<<<64, 512, 0, stream>>>(yh + qo, yl + qo, xh + qo, xl + qo, S);
      k_softmax<<<NN / 4, 256, 0, stream>>>(S, c2 + (size_t)b * NN, NN);
      k_gemm_out<<<128, 256, 0, stream>>>((const u16*)S, woutT, bout, out + qo);
    }
  } else {
    // Tier C (60 MiB): per 2-batch chunk, xh/xl 16MB, yh/yl 16MB, S 16MB
    u16* xh = (u16*)(base);
    u16* xl = (u16*)(base + 8 * MB);
    u16* yh = (u16*)(base + 16 * MB);
    u16* yl = (u16*)(base + 24 * MB);
    char* R = base + 32 * MB;
    u16* wqh = (u16*)(R);
    u16* wql = (u16*)(R + 2 * MB);
    u16* wkh = (u16*)(R + 4 * MB);
    u16* wkl = (u16*)(R + 6 * MB);
    float* S = (float*)R;

    k_split<<<256, 256, 0, stream>>>(Wq, wqh, wql, (long)DD * DD / 4);
    k_split<<<256, 256, 0, stream>>>(Wk, wkh, wkl, (long)DD * DD / 4);
    k_gemm_y8<<<16, 512, 0, stream>>>(wkh, wkl, wqh, wql, mth, mtl);
    k_transpose_split<<<dim3(32, 64, 1), tb, 0, stream>>>(Wout, woutT, 2048, 1024);
    k_matvec<<<256, 256, 0, stream>>>(Wk, bq, v2, DD);
    k_matvec<<<4096, 256, 0, stream>>>(x, v2, c2, DD);
    for (int c = 0; c < 4; c++) {
      size_t xo = (size_t)c * 2 * NN * DD;
      k_split<<<1024, 256, 0, stream>>>(x + xo, xh, xl, (long)2 * NN * DD / 4);
      k_gemm_y8<<<64, 512, 0, stream>>>(xh, xl, mth, mtl, yh, yl);
      for (int bi = 0; bi < 2; bi++) {
        size_t lo = (size_t)bi * NN * DD;
        k_gemm_s8<<<64, 512, 0, stream>>>(yh + lo, yl + lo, xh + lo, xl + lo, S);
        k_softmax<<<NN / 4, 256, 0, stream>>>(S, c2 + (size_t)(c * 2 + bi) * NN, NN);
        k_gemm_out<<<128, 256, 0, stream>>>((const u16*)S, woutT, bout, out + xo + lo);
      }
    }
  }
}